// Round 4
// baseline (289.455 us; speedup 1.0000x reference)
//
#include <hip/hip_runtime.h>
#include <stdint.h>

// SoftALU: inputs are EXACT one-hot byte encodings; softmax(100*x) collapses
// to hard integer ALU (cold probs ~ exp(-100) ~ 0, below the 2e-2 threshold).
// Strategy:
//   1. hipMemsetAsync(d_out, 0)  -- 224 MiB of zeros at rocclr-fill speed
//      (measured 6.4-6.6 TB/s on this chip via the harness's own fills).
//   2. decode_scatter kernel     -- read 64 MiB one-hots, decode uint32 a,b,
//      compute {add,sub,mul,div,and,or,xor}, store ONLY the 28 hot 1.0f
//      elements per batch (229K scattered dwords total, ~0.9 MB).

typedef float vfloat4 __attribute__((ext_vector_type(4)));

__global__ __launch_bounds__(256) void decode_scatter_kernel(const float* __restrict__ a,
                                                             const float* __restrict__ b,
                                                             float* __restrict__ out,
                                                             int B) {
    const int batch = blockIdx.x;
    const int t = threadIdx.x;

    __shared__ uint32_t sh_bytes[8];  // a byte0..3, b byte0..3 (byte n = bits 8n..8n+7)

    // Each batch operand = 4 rows x 256 floats = 256 float4. Thread t reads
    // float4 t of a and of b (fully coalesced, 16B/lane).
    const vfloat4* va = (const vfloat4*)(a + (size_t)batch * 1024);
    const vfloat4* vb = (const vfloat4*)(b + (size_t)batch * 1024);
    const vfloat4 xa = va[t];
    const vfloat4 xb = vb[t];
    const int row = t >> 6;          // which of the 4 bytes
    const int pos0 = (t & 63) * 4;   // float index within the 256-row
#pragma unroll
    for (int j = 0; j < 4; ++j) {
        if (xa[j] > 0.5f) sh_bytes[row] = (uint32_t)(pos0 + j);
        if (xb[j] > 0.5f) sh_bytes[4 + row] = (uint32_t)(pos0 + j);
    }
    __syncthreads();

    // All threads compute the (block-uniform) results; threads 0..27 scatter.
    const uint32_t av = sh_bytes[0] | (sh_bytes[1] << 8) | (sh_bytes[2] << 16) | (sh_bytes[3] << 24);
    const uint32_t bv = sh_bytes[4] | (sh_bytes[5] << 8) | (sh_bytes[6] << 16) | (sh_bytes[7] << 24);
    if (t < 28) {
        const int op = t >> 2;   // 0..6
        const int n  = t & 3;    // byte index
        uint32_t r;
        switch (op) {
            case 0: r = av + bv; break;               // soft_add(a,b)
            case 1: r = av - bv; break;               // a + negate(b) mod 2^32
            case 2: r = av * bv; break;               // wrapping mul
            case 3: r = bv ? (av / bv) : 0u; break;   // div, 0 when b==0
            case 4: r = av & bv; break;
            case 5: r = av | bv; break;
            default: r = av ^ bv; break;
        }
        const int rb = (int)((r >> (8 * n)) & 255u);
        out[(((size_t)op * B + batch) * 4 + n) * 256 + rb] = 1.0f;
    }
}

extern "C" void kernel_launch(void* const* d_in, const int* in_sizes, int n_in,
                              void* d_out, int out_size, void* d_ws, size_t ws_size,
                              hipStream_t stream) {
    const float* a = (const float*)d_in[0];
    const float* b = (const float*)d_in[1];
    float* out = (float*)d_out;
    const int B = in_sizes[0] / (4 * 256);  // 8192

    // Bulk zeros at fill speed (graph-capturable memset node).
    hipMemsetAsync(out, 0, (size_t)out_size * sizeof(float), stream);
    // Scatter the 7*4 hot ones per batch.
    decode_scatter_kernel<<<B, 256, 0, stream>>>(a, b, out, B);
}